// Round 5
// baseline (505.940 us; speedup 1.0000x reference)
//
#include <hip/hip_runtime.h>

// K-Sparse Autoencoder fwd: B=4096, D=768, H=16384, K=32
// Determinism notes (tripwire discipline):
//  - no cross-call state: every ws/d_out byte read within a call is written earlier in that call
//  - candidate SET is deterministic (full bisection, CAND_MAX=512 >> worst-case ~90)
//  - top-32 is order-independent (total order on (value desc, index asc)); padding uses si=-1
//  - all LDS write->read hand-offs are separated by __syncthreads() (full LDS fence)
constexpr int NB = 4096;
constexpr int ND = 768;
constexpr int NH = 16384;
constexpr int NK = 32;
constexpr int CAND_MAX = 512;
#define DELTA 0.10f   // bf16-MFMA accum err + bf16 za quantization <= ~0.02 worst; 5x margin

typedef __bf16 bf16x8 __attribute__((ext_vector_type(8)));
typedef float  f32x4  __attribute__((ext_vector_type(4)));

// ---------------- workspace layout (bytes) ----------------
constexpr size_t OFF_XBF   = 0;                                     // x bf16      [NB][ND]
constexpr size_t OFF_WENCB = OFF_XBF   + (size_t)NB * ND * 2;       // W_enc bf16  [NH][ND]
constexpr size_t OFF_WDECT = OFF_WENCB + (size_t)NH * ND * 2;       // W_dec^T f32 [NH][ND]
constexpr size_t OFF_CIDX  = OFF_WDECT + (size_t)NH * ND * 4;       // cand_idx [NB][CAND_MAX]
constexpr size_t OFF_CCNT  = OFF_CIDX  + (size_t)NB * CAND_MAX * 4; // cand_cnt [NB]

__device__ inline unsigned short f2bf(float f) {
  unsigned u = __float_as_uint(f);
  unsigned r = u + 0x7fffu + ((u >> 16) & 1u);   // RNE
  return (unsigned short)(r >> 16);
}

__device__ __forceinline__ void gld_lds16(const unsigned short* g, unsigned short* s) {
  // async global->LDS, 16B/lane; LDS dest = wave-uniform base + lane*16 (HW rule)
  __builtin_amdgcn_global_load_lds((const __attribute__((address_space(1))) void*)g,
                                   (__attribute__((address_space(3))) void*)s, 16, 0, 0);
}

// ---------------- K1: f32 -> bf16 cast ----------------
__global__ __launch_bounds__(256) void cast_bf16_kernel(const float* __restrict__ in,
                                                        unsigned short* __restrict__ out,
                                                        int n4) {
  int stride = gridDim.x * 256;
  for (int i = blockIdx.x * 256 + threadIdx.x; i < n4; i += stride) {
    float4 v = ((const float4*)in)[i];
    unsigned long long p = (unsigned long long)f2bf(v.x)
                         | ((unsigned long long)f2bf(v.y) << 16)
                         | ((unsigned long long)f2bf(v.z) << 32)
                         | ((unsigned long long)f2bf(v.w) << 48);
    ((unsigned long long*)out)[i] = p;
  }
}

// ---------------- K2: transpose W_dec [ND][NH] -> [NH][ND] f32 ----------------
__global__ __launch_bounds__(256) void transpose_kernel(const float* __restrict__ in,
                                                        float* __restrict__ out) {
  __shared__ float tile[32][33];
  int hb = blockIdx.x * 32, db = blockIdx.y * 32;
  int tx = threadIdx.x, ty = threadIdx.y;   // 32 x 8
#pragma unroll
  for (int i = 0; i < 4; ++i)
    tile[ty + i * 8][tx] = in[(size_t)(db + ty + i * 8) * NH + hb + tx];
  __syncthreads();
#pragma unroll
  for (int i = 0; i < 4; ++i)
    out[(size_t)(hb + ty + i * 8) * ND + db + tx] = tile[tx][ty + i * 8];
}

// ---------------- K3: encode GEMM (bf16 MFMA) -> za bf16 (round-4 proven, unchanged) ----------------
__global__ __launch_bounds__(256) void encode_gemm_kernel(
    const unsigned short* __restrict__ Abf,   // [NB][ND]
    const unsigned short* __restrict__ Bbf,   // [NH][ND]
    const float* __restrict__ b_enc,
    unsigned short* __restrict__ za) {        // [NB][NH] bf16
  __shared__ __align__(16) unsigned short As[128 * 64];   // 16 KB
  __shared__ __align__(16) unsigned short Bs[128 * 64];   // 16 KB

  // super-tile mapping (bijective): per XCD, 8bm x 8bn chunks -> A+B slices L2-resident
  int bid = blockIdx.x;                 // 0..4095
  int x  = bid & 7;                     // XCD
  int j  = bid >> 3;                    // 0..511 within XCD
  int st = j >> 6;                      // 0..7: super-tile slot
  int w  = j & 63;                      // 0..63 within super-tile
  int g  = st * 8 + x;                  // global super-tile 0..63 (4 sm x 16 sn)
  int bm = (g & 3) * 8 + (w & 7);       // 0..31
  int bn = (g >> 2) * 8 + (w >> 3);     // 0..127
  int m0 = bm * 128, n0 = bn * 128;

  int tid = threadIdx.x, wid = tid >> 6, l = tid & 63;
  int wr = wid >> 1, wc = wid & 1;
  int lr = l & 15, lk = l >> 4;

  int srow = l >> 3;
  int scol = (l & 7) ^ srow;            // pre-swizzled global source (rule #21)

  f32x4 acc[4][4] = {};

  for (int kt = 0; kt < 12; ++kt) {     // ND/64
    __syncthreads();                    // prior tile's ds_reads done before overwrite
#pragma unroll
    for (int t = 0; t < 4; ++t) {
      int c = wid * 4 + t;              // 16 chunks x 8 rows = 128 rows
      gld_lds16(Abf + ((size_t)(m0 + c * 8 + srow) * ND + kt * 64 + scol * 8), &As[c * 512]);
      gld_lds16(Bbf + ((size_t)(n0 + c * 8 + srow) * ND + kt * 64 + scol * 8), &Bs[c * 512]);
    }
    asm volatile("s_waitcnt vmcnt(0)" ::: "memory");
    __syncthreads();                    // tiles resident
#pragma unroll
    for (int kk = 0; kk < 2; ++kk) {
      bf16x8 af[4], bq[4];
      int u = (kk * 4 + lk) ^ (lr & 7);          // swizzled 16B unit
#pragma unroll
      for (int i = 0; i < 4; ++i)
        af[i] = *(const bf16x8*)&As[(wr * 64 + i * 16 + lr) * 64 + u * 8];
#pragma unroll
      for (int j2 = 0; j2 < 4; ++j2)
        bq[j2] = *(const bf16x8*)&Bs[(wc * 64 + j2 * 16 + lr) * 64 + u * 8];
#pragma unroll
      for (int i = 0; i < 4; ++i)
#pragma unroll
        for (int j2 = 0; j2 < 4; ++j2)
          acc[i][j2] = __builtin_amdgcn_mfma_f32_16x16x32_bf16(af[i], bq[j2], acc[i][j2], 0, 0, 0);
    }
  }

  // ---- epilogue: bias+relu -> bf16, stage via LDS, coalesced 16B stores ----
  __syncthreads();
  unsigned short* ep = (wid < 2) ? &As[wid * 4096] : &Bs[(wid - 2) * 4096]; // [64][64]/wave
#pragma unroll
  for (int j2 = 0; j2 < 4; ++j2) {
    float bias = b_enc[n0 + wc * 64 + j2 * 16 + lr];
#pragma unroll
    for (int i = 0; i < 4; ++i) {
#pragma unroll
      for (int q = 0; q < 4; ++q) {
        int row = i * 16 + lk * 4 + q;  // local m (C/D: row=(l>>4)*4+q)
        int col = j2 * 16 + lr;         // local n (col=l&15)
        float v = fmaxf(acc[i][j2][q] + bias, 0.0f);
        ep[row * 64 + (((col >> 3) ^ (row & 7)) * 8) + (col & 7)] = f2bf(v);
      }
    }
  }
  __syncthreads();                     // FENCE: LDS writes visible before readback
#pragma unroll
  for (int t = 0; t < 8; ++t) {
    int row = t * 8 + (l >> 3);
    int u = (l & 7) ^ (row & 7);
    int4 d = *(const int4*)&ep[row * 64 + u * 8];
    *(int4*)(za + (size_t)(m0 + wr * 64 + row) * NH + n0 + wc * 64 + (l & 7) * 8) = d;
  }
}

// ---------------- K4: per-row rank-32 threshold (full bf16 bisection) + candidates ----------------
__global__ __launch_bounds__(256) void select_kernel(const unsigned short* __restrict__ za,
                                                     int* __restrict__ cand_idx,
                                                     int* __restrict__ cand_cnt) {
  int b = blockIdx.x, tid = threadIdx.x;
  const uint4* zrow = (const uint4*)(za + (size_t)b * NH);
  uint4 v[8];
#pragma unroll
  for (int i = 0; i < 8; ++i) v[i] = zrow[tid + 256 * i];

  __shared__ int wcnt[4];
  __shared__ int lcnt;

  unsigned lo = 0u, hi = 0x7F80u;   // bf16 bits; za >= 0 -> order-preserving
  for (int it = 0; it < 15; ++it) {
    unsigned mid = (lo + hi) >> 1;
    int c = 0;
#pragma unroll
    for (int i = 0; i < 8; ++i) {
      const unsigned* p = (const unsigned*)&v[i];
#pragma unroll
      for (int e = 0; e < 4; ++e) {
        unsigned u = p[e];
        c += ((u & 0xFFFFu) >= mid) ? 1 : 0;
        c += ((u >> 16) >= mid) ? 1 : 0;
      }
    }
#pragma unroll
    for (int off = 32; off; off >>= 1) c += __shfl_xor(c, off, 64);
    if ((tid & 63) == 0) wcnt[tid >> 6] = c;
    __syncthreads();
    int tot = wcnt[0] + wcnt[1] + wcnt[2] + wcnt[3];
    __syncthreads();
    if (tot >= NK) lo = mid; else hi = mid;
  }

  float thr = __uint_as_float(lo << 16) - DELTA;
  if (thr < 1e-12f) thr = 1e-12f;   // degenerate rows: strict positives only
  if (tid == 0) lcnt = 0;
  __syncthreads();
#pragma unroll
  for (int i = 0; i < 8; ++i) {
    const unsigned* p = (const unsigned*)&v[i];
#pragma unroll
    for (int e = 0; e < 4; ++e) {
      unsigned u = p[e];
      int hbase = (tid + 256 * i) * 8 + e * 2;
      float f0 = __uint_as_float((u & 0xFFFFu) << 16);
      float f1 = __uint_as_float(u & 0xFFFF0000u);
      if (f0 >= thr) { int s = atomicAdd(&lcnt, 1); if (s < CAND_MAX) cand_idx[(size_t)b * CAND_MAX + s] = hbase; }
      if (f1 >= thr) { int s = atomicAdd(&lcnt, 1); if (s < CAND_MAX) cand_idx[(size_t)b * CAND_MAX + s] = hbase + 1; }
    }
  }
  __syncthreads();
  if (tid == 0) cand_cnt[b] = (lcnt < CAND_MAX) ? lcnt : CAND_MAX;
}

// ---------------- K4b: streaming zero-fill of z region (za bf16 is dead after select) ----------------
__global__ __launch_bounds__(256) void zero_z_kernel(float4* __restrict__ z4, int n) {
  int stride = gridDim.x * 256;
  float4 z = make_float4(0.f, 0.f, 0.f, 0.f);
  for (int i = blockIdx.x * 256 + threadIdx.x; i < n; i += stride) z4[i] = z;
}

// ---------------- K5: exact recompute + top-32 + scatter + sparse decode ----------------
__global__ __launch_bounds__(256) void finalize_kernel(
    const float* __restrict__ x, const float* __restrict__ W_enc,
    const float* __restrict__ b_enc,
    const int* __restrict__ cand_idx, const int* __restrict__ cand_cnt,
    const float* __restrict__ WdecT, const float* __restrict__ b_dec,
    float* __restrict__ zout, float* __restrict__ xhat) {
  int b = blockIdx.x, tid = threadIdx.x;
  int wid = tid >> 6, l = tid & 63;
  __shared__ __align__(16) float xr[ND];
  __shared__ float cv[CAND_MAX];
  __shared__ int   ci[CAND_MAX];
  __shared__ float sv[NK];
  __shared__ int   si[NK];

  int cnt = cand_cnt[b];
  {
    const float4* xrow = (const float4*)(x + (size_t)b * ND);
    for (int i = tid; i < ND / 4; i += 256) ((float4*)xr)[i] = xrow[i];
    for (int c = tid; c < cnt; c += 256) ci[c] = cand_idx[(size_t)b * CAND_MAX + c];
  }
  __syncthreads();

  // exact f32 dot per candidate, one wave each, float4-vectorized (3x dwordx4 per lane)
  const float4* xr4 = (const float4*)xr;
  for (int c = wid; c < cnt; c += 4) {
    int h = ci[c];
    const float4* wrow4 = (const float4*)(W_enc + (size_t)h * ND);
    float4 s4 = make_float4(0.f, 0.f, 0.f, 0.f);
#pragma unroll
    for (int i = 0; i < 3; ++i) {        // 192 float4 per row = 3 x 64 lanes
      float4 wv = wrow4[l + 64 * i];
      float4 xv = xr4[l + 64 * i];
      s4.x = fmaf(wv.x, xv.x, s4.x);
      s4.y = fmaf(wv.y, xv.y, s4.y);
      s4.z = fmaf(wv.z, xv.z, s4.z);
      s4.w = fmaf(wv.w, xv.w, s4.w);
    }
    float s = (s4.x + s4.y) + (s4.z + s4.w);
#pragma unroll
    for (int off = 32; off; off >>= 1) s += __shfl_xor(s, off, 64);
    if (l == 0) cv[c] = fmaxf(s + b_enc[h], 0.f);
  }
  __syncthreads();

  // wave 0: deterministic top-32 by (value desc, index asc) — total order, set-deterministic
  if (wid == 0) {
    float lv[8]; int lh[8];
#pragma unroll
    for (int ii = 0; ii < 8; ++ii) {
      int c = l + 64 * ii;
      if (c < cnt) { lv[ii] = cv[c]; lh[ii] = ci[c]; }
      else         { lv[ii] = -1.f;  lh[ii] = 0x7fffffff; }
    }
    for (int r = 0; r < NK; ++r) {
      float bv = -1.f; int bh = 0x7fffffff; int bl = l; int bii = 0;
#pragma unroll
      for (int ii = 0; ii < 8; ++ii)
        if (lv[ii] > bv || (lv[ii] == bv && lh[ii] < bh)) { bv = lv[ii]; bh = lh[ii]; bii = ii; }
#pragma unroll
      for (int off = 32; off; off >>= 1) {
        float ov = __shfl_xor(bv, off, 64);
        int   oh = __shfl_xor(bh, off, 64);
        int   ol = __shfl_xor(bl, off, 64);
        int   oi = __shfl_xor(bii, off, 64);
        if (ov > bv || (ov == bv && oh < bh)) { bv = ov; bh = oh; bl = ol; bii = oi; }
      }
      if (l == 0) {
        if (bv > -0.5f) { sv[r] = bv; si[r] = bh; }
        else            { sv[r] = 0.f; si[r] = -1; }   // sentinel: no write collision
      }
#pragma unroll
      for (int ii = 0; ii < 8; ++ii)
        if (ii == bii && l == bl && bv > -0.5f) lv[ii] = -1.f;  // retire winner
    }
  }
  __syncthreads();

  // scatter exact top-32 into pre-zeroed z (guarded: padding never writes)
  if (tid < NK) {
    int s = si[tid];
    if (s >= 0) zout[(size_t)b * NH + s] = sv[tid];
  }

  // sparse decode, float4: xhat[b,:] = b_dec + sum_j sv[j] * WdecT[si[j],:]
  if (tid < ND / 4) {                    // 192 active lanes
    float4 a = ((const float4*)b_dec)[tid];
#pragma unroll 8
    for (int j = 0; j < NK; ++j) {
      int hj = si[j]; hj = (hj < 0) ? 0 : hj;
      float vj = sv[j];                  // 0 for padding -> no contribution
      float4 wv = ((const float4*)(WdecT + (size_t)hj * ND))[tid];
      a.x = fmaf(vj, wv.x, a.x);
      a.y = fmaf(vj, wv.y, a.y);
      a.z = fmaf(vj, wv.z, a.z);
      a.w = fmaf(vj, wv.w, a.w);
    }
    ((float4*)(xhat + (size_t)b * ND))[tid] = a;
  }
}

// ---------------- launcher ----------------
extern "C" void kernel_launch(void* const* d_in, const int* in_sizes, int n_in,
                              void* d_out, int out_size, void* d_ws, size_t ws_size,
                              hipStream_t stream) {
  const float* x     = (const float*)d_in[0];
  const float* W_enc = (const float*)d_in[1];
  const float* b_enc = (const float*)d_in[2];
  const float* W_dec = (const float*)d_in[3];
  const float* b_dec = (const float*)d_in[4];

  float* xhat = (float*)d_out;
  float* zout = (float*)d_out + (size_t)NB * ND;       // final z (f32)
  unsigned short* za = (unsigned short*)zout;          // approx z (bf16) reuses z region

  char* ws = (char*)d_ws;
  unsigned short* x_bf    = (unsigned short*)(ws + OFF_XBF);
  unsigned short* wenc_bf = (unsigned short*)(ws + OFF_WENCB);
  float*          wdecT   = (float*)(ws + OFF_WDECT);
  int*            cidx    = (int*)(ws + OFF_CIDX);
  int*            ccnt    = (int*)(ws + OFF_CCNT);

  cast_bf16_kernel<<<1024, 256, 0, stream>>>(x, x_bf, NB * ND / 4);
  cast_bf16_kernel<<<2048, 256, 0, stream>>>(W_enc, wenc_bf, NH * ND / 4);
  transpose_kernel<<<dim3(NH / 32, ND / 32), dim3(32, 8), 0, stream>>>(W_dec, wdecT);
  encode_gemm_kernel<<<(NB / 128) * (NH / 128), 256, 0, stream>>>(x_bf, wenc_bf, b_enc, za);
  select_kernel<<<NB, 256, 0, stream>>>(za, cidx, ccnt);
  zero_z_kernel<<<2048, 256, 0, stream>>>((float4*)zout, NB * NH / 4);
  finalize_kernel<<<NB, 256, 0, stream>>>(x, W_enc, b_enc, cidx, ccnt, wdecT, b_dec, zout, xhat);
}

// Round 6
// 459.011 us; speedup vs baseline: 1.1022x; 1.1022x over previous
//
#include <hip/hip_runtime.h>

// K-Sparse Autoencoder fwd: B=4096, D=768, H=16384, K=32
// Determinism notes (tripwire discipline):
//  - no cross-call state: every ws/d_out byte read within a call is written earlier in that call
//  - candidate SET is deterministic (bisection + early-exit are pure functions of data;
//    CAND_MAX=512 >> worst-case ~183 so no truncation cliff)
//  - top-32 is order-independent (total order on (value desc, index asc)); padding uses si=-1
//  - all LDS write->read hand-offs are separated by __syncthreads() (full LDS fence)
//  - z zero-fill inside finalize is safe: za (aliasing z region) is dead after select
constexpr int NB = 4096;
constexpr int ND = 768;
constexpr int NH = 16384;
constexpr int NK = 32;
constexpr int CAND_MAX = 512;
#define DELTA 0.04f   // = 2*(6-sigma MFMA err 0.012 + bf16 store quant 0.0045), sigma~0.002

typedef __bf16 bf16x8 __attribute__((ext_vector_type(8)));
typedef float  f32x4  __attribute__((ext_vector_type(4)));

// ---------------- workspace layout (bytes) ----------------
constexpr size_t OFF_XBF   = 0;                                     // x bf16      [NB][ND]
constexpr size_t OFF_WENCB = OFF_XBF   + (size_t)NB * ND * 2;       // W_enc bf16  [NH][ND]
constexpr size_t OFF_WDECT = OFF_WENCB + (size_t)NH * ND * 2;       // W_dec^T f32 [NH][ND]
constexpr size_t OFF_CIDX  = OFF_WDECT + (size_t)NH * ND * 4;       // cand_idx [NB][CAND_MAX]
constexpr size_t OFF_CCNT  = OFF_CIDX  + (size_t)NB * CAND_MAX * 4; // cand_cnt [NB]

__device__ inline unsigned short f2bf(float f) {
  unsigned u = __float_as_uint(f);
  unsigned r = u + 0x7fffu + ((u >> 16) & 1u);   // RNE
  return (unsigned short)(r >> 16);
}

__device__ __forceinline__ void gld_lds16(const unsigned short* g, unsigned short* s) {
  // async global->LDS, 16B/lane; LDS dest = wave-uniform base + lane*16 (HW rule)
  __builtin_amdgcn_global_load_lds((const __attribute__((address_space(1))) void*)g,
                                   (__attribute__((address_space(3))) void*)s, 16, 0, 0);
}

// ---------------- K1: f32 -> bf16 cast ----------------
__global__ __launch_bounds__(256) void cast_bf16_kernel(const float* __restrict__ in,
                                                        unsigned short* __restrict__ out,
                                                        int n4) {
  int stride = gridDim.x * 256;
  for (int i = blockIdx.x * 256 + threadIdx.x; i < n4; i += stride) {
    float4 v = ((const float4*)in)[i];
    unsigned long long p = (unsigned long long)f2bf(v.x)
                         | ((unsigned long long)f2bf(v.y) << 16)
                         | ((unsigned long long)f2bf(v.z) << 32)
                         | ((unsigned long long)f2bf(v.w) << 48);
    ((unsigned long long*)out)[i] = p;
  }
}

// ---------------- K2: transpose W_dec [ND][NH] -> [NH][ND] f32 ----------------
__global__ __launch_bounds__(256) void transpose_kernel(const float* __restrict__ in,
                                                        float* __restrict__ out) {
  __shared__ float tile[32][33];
  int hb = blockIdx.x * 32, db = blockIdx.y * 32;
  int tx = threadIdx.x, ty = threadIdx.y;   // 32 x 8
#pragma unroll
  for (int i = 0; i < 4; ++i)
    tile[ty + i * 8][tx] = in[(size_t)(db + ty + i * 8) * NH + hb + tx];
  __syncthreads();
#pragma unroll
  for (int i = 0; i < 4; ++i)
    out[(size_t)(hb + ty + i * 8) * ND + db + tx] = tile[tx][ty + i * 8];
}

// ---------------- K3: encode GEMM (bf16 MFMA) -> za bf16 (round-4 proven, unchanged) ----------------
__global__ __launch_bounds__(256) void encode_gemm_kernel(
    const unsigned short* __restrict__ Abf,   // [NB][ND]
    const unsigned short* __restrict__ Bbf,   // [NH][ND]
    const float* __restrict__ b_enc,
    unsigned short* __restrict__ za) {        // [NB][NH] bf16
  __shared__ __align__(16) unsigned short As[128 * 64];   // 16 KB
  __shared__ __align__(16) unsigned short Bs[128 * 64];   // 16 KB

  // super-tile mapping (bijective): per XCD, 8bm x 8bn chunks -> A+B slices L2-resident
  int bid = blockIdx.x;                 // 0..4095
  int x  = bid & 7;                     // XCD
  int j  = bid >> 3;                    // 0..511 within XCD
  int st = j >> 6;                      // 0..7: super-tile slot
  int w  = j & 63;                      // 0..63 within super-tile
  int g  = st * 8 + x;                  // global super-tile 0..63 (4 sm x 16 sn)
  int bm = (g & 3) * 8 + (w & 7);       // 0..31
  int bn = (g >> 2) * 8 + (w >> 3);     // 0..127
  int m0 = bm * 128, n0 = bn * 128;

  int tid = threadIdx.x, wid = tid >> 6, l = tid & 63;
  int wr = wid >> 1, wc = wid & 1;
  int lr = l & 15, lk = l >> 4;

  int srow = l >> 3;
  int scol = (l & 7) ^ srow;            // pre-swizzled global source (rule #21)

  f32x4 acc[4][4] = {};

  for (int kt = 0; kt < 12; ++kt) {     // ND/64
    __syncthreads();                    // prior tile's ds_reads done before overwrite
#pragma unroll
    for (int t = 0; t < 4; ++t) {
      int c = wid * 4 + t;              // 16 chunks x 8 rows = 128 rows
      gld_lds16(Abf + ((size_t)(m0 + c * 8 + srow) * ND + kt * 64 + scol * 8), &As[c * 512]);
      gld_lds16(Bbf + ((size_t)(n0 + c * 8 + srow) * ND + kt * 64 + scol * 8), &Bs[c * 512]);
    }
    asm volatile("s_waitcnt vmcnt(0)" ::: "memory");
    __syncthreads();                    // tiles resident
#pragma unroll
    for (int kk = 0; kk < 2; ++kk) {
      bf16x8 af[4], bq[4];
      int u = (kk * 4 + lk) ^ (lr & 7);          // swizzled 16B unit
#pragma unroll
      for (int i = 0; i < 4; ++i)
        af[i] = *(const bf16x8*)&As[(wr * 64 + i * 16 + lr) * 64 + u * 8];
#pragma unroll
      for (int j2 = 0; j2 < 4; ++j2)
        bq[j2] = *(const bf16x8*)&Bs[(wc * 64 + j2 * 16 + lr) * 64 + u * 8];
#pragma unroll
      for (int i = 0; i < 4; ++i)
#pragma unroll
        for (int j2 = 0; j2 < 4; ++j2)
          acc[i][j2] = __builtin_amdgcn_mfma_f32_16x16x32_bf16(af[i], bq[j2], acc[i][j2], 0, 0, 0);
    }
  }

  // ---- epilogue: bias+relu -> bf16, stage via LDS, coalesced 16B stores ----
  __syncthreads();
  unsigned short* ep = (wid < 2) ? &As[wid * 4096] : &Bs[(wid - 2) * 4096]; // [64][64]/wave
#pragma unroll
  for (int j2 = 0; j2 < 4; ++j2) {
    float bias = b_enc[n0 + wc * 64 + j2 * 16 + lr];
#pragma unroll
    for (int i = 0; i < 4; ++i) {
#pragma unroll
      for (int q = 0; q < 4; ++q) {
        int row = i * 16 + lk * 4 + q;  // local m (C/D: row=(l>>4)*4+q)
        int col = j2 * 16 + lr;         // local n (col=l&15)
        float v = fmaxf(acc[i][j2][q] + bias, 0.0f);
        ep[row * 64 + (((col >> 3) ^ (row & 7)) * 8) + (col & 7)] = f2bf(v);
      }
    }
  }
  __syncthreads();                     // FENCE: LDS writes visible before readback
#pragma unroll
  for (int t = 0; t < 8; ++t) {
    int row = t * 8 + (l >> 3);
    int u = (l & 7) ^ (row & 7);
    int4 d = *(const int4*)&ep[row * 64 + u * 8];
    *(int4*)(za + (size_t)(m0 + wr * 64 + row) * NH + n0 + wc * 64 + (l & 7) * 8) = d;
  }
}

// ---------------- K4: per-row rank-32 threshold (bf16 bisection, deterministic early-exit) ----------------
__global__ __launch_bounds__(256) void select_kernel(const unsigned short* __restrict__ za,
                                                     int* __restrict__ cand_idx,
                                                     int* __restrict__ cand_cnt) {
  int b = blockIdx.x, tid = threadIdx.x;
  const uint4* zrow = (const uint4*)(za + (size_t)b * NH);
  uint4 v[8];
#pragma unroll
  for (int i = 0; i < 8; ++i) v[i] = zrow[tid + 256 * i];

  __shared__ int wcnt[4];
  __shared__ int lcnt;

  unsigned lo = 0u, hi = 0x7F80u;   // bf16 bits; za >= 0 -> order-preserving
  for (int it = 0; it < 15; ++it) {
    unsigned mid = (lo + hi) >> 1;
    int c = 0;
#pragma unroll
    for (int i = 0; i < 8; ++i) {
      const unsigned* p = (const unsigned*)&v[i];
#pragma unroll
      for (int e = 0; e < 4; ++e) {
        unsigned u = p[e];
        c += ((u & 0xFFFFu) >= mid) ? 1 : 0;
        c += ((u >> 16) >= mid) ? 1 : 0;
      }
    }
#pragma unroll
    for (int off = 32; off; off >>= 1) c += __shfl_xor(c, off, 64);
    if ((tid & 63) == 0) wcnt[tid >> 6] = c;
    __syncthreads();
    int tot = wcnt[0] + wcnt[1] + wcnt[2] + wcnt[3];
    __syncthreads();
    if (tot >= NK) {
      lo = mid;
      if (tot <= 128) break;        // deterministic early-exit: 32 <= count(za>=lo) <= 128
    } else {
      hi = mid;
    }
  }

  float thr = __uint_as_float(lo << 16) - DELTA;
  if (thr < 1e-12f) thr = 1e-12f;   // degenerate rows: strict positives only
  if (tid == 0) lcnt = 0;
  __syncthreads();
#pragma unroll
  for (int i = 0; i < 8; ++i) {
    const unsigned* p = (const unsigned*)&v[i];
#pragma unroll
    for (int e = 0; e < 4; ++e) {
      unsigned u = p[e];
      int hbase = (tid + 256 * i) * 8 + e * 2;
      float f0 = __uint_as_float((u & 0xFFFFu) << 16);
      float f1 = __uint_as_float(u & 0xFFFF0000u);
      if (f0 >= thr) { int s = atomicAdd(&lcnt, 1); if (s < CAND_MAX) cand_idx[(size_t)b * CAND_MAX + s] = hbase; }
      if (f1 >= thr) { int s = atomicAdd(&lcnt, 1); if (s < CAND_MAX) cand_idx[(size_t)b * CAND_MAX + s] = hbase + 1; }
    }
  }
  __syncthreads();
  if (tid == 0) cand_cnt[b] = (lcnt < CAND_MAX) ? lcnt : CAND_MAX;
}

// ---------------- K5: zero z row (early, overlapped) + exact recompute + top-32 + scatter + decode ----------------
__global__ __launch_bounds__(256) void finalize_kernel(
    const float* __restrict__ x, const float* __restrict__ W_enc,
    const float* __restrict__ b_enc,
    const int* __restrict__ cand_idx, const int* __restrict__ cand_cnt,
    const float* __restrict__ WdecT, const float* __restrict__ b_dec,
    float* __restrict__ zout, float* __restrict__ xhat) {
  int b = blockIdx.x, tid = threadIdx.x;
  int wid = tid >> 6, l = tid & 63;
  __shared__ __align__(16) float xr[ND];
  __shared__ float cv[CAND_MAX];
  __shared__ int   ci[CAND_MAX];
  __shared__ float sv[NK];
  __shared__ int   si[NK];

  int cnt = cand_cnt[b];
  {
    const float4* xrow = (const float4*)(x + (size_t)b * ND);
    for (int i = tid; i < ND / 4; i += 256) ((float4*)xr)[i] = xrow[i];
    for (int c = tid; c < cnt; c += 256) ci[c] = cand_idx[(size_t)b * CAND_MAX + c];
  }

  // zero-fill z row b EARLY: fire-and-forget stores that overlap the gather latency below.
  // Safe: za (which aliases this region) is dead after select; scatter comes after barrier.
  {
    float4 z4 = make_float4(0.f, 0.f, 0.f, 0.f);
    float4* zr = (float4*)(zout + (size_t)b * NH);
#pragma unroll
    for (int i = 0; i < NH / 4 / 256; ++i) zr[tid + 256 * i] = z4;   // 16 stores/thread
  }
  __syncthreads();

  // exact f32 dot per candidate, one wave each, float4-vectorized
  const float4* xr4 = (const float4*)xr;
  for (int c = wid; c < cnt; c += 4) {
    int h = ci[c];
    const float4* wrow4 = (const float4*)(W_enc + (size_t)h * ND);
    float4 s4 = make_float4(0.f, 0.f, 0.f, 0.f);
#pragma unroll
    for (int i = 0; i < 3; ++i) {        // 192 float4 per row = 3 x 64 lanes
      float4 wv = wrow4[l + 64 * i];
      float4 xv = xr4[l + 64 * i];
      s4.x = fmaf(wv.x, xv.x, s4.x);
      s4.y = fmaf(wv.y, xv.y, s4.y);
      s4.z = fmaf(wv.z, xv.z, s4.z);
      s4.w = fmaf(wv.w, xv.w, s4.w);
    }
    float s = (s4.x + s4.y) + (s4.z + s4.w);
#pragma unroll
    for (int off = 32; off; off >>= 1) s += __shfl_xor(s, off, 64);
    if (l == 0) cv[c] = fmaxf(s + b_enc[h], 0.f);
  }
  __syncthreads();

  // wave 0: deterministic top-32 by (value desc, index asc) — total order, set-deterministic
  if (wid == 0) {
    float lv[8]; int lh[8];
#pragma unroll
    for (int ii = 0; ii < 8; ++ii) {
      int c = l + 64 * ii;
      if (c < cnt) { lv[ii] = cv[c]; lh[ii] = ci[c]; }
      else         { lv[ii] = -1.f;  lh[ii] = 0x7fffffff; }
    }
    for (int r = 0; r < NK; ++r) {
      float bv = -1.f; int bh = 0x7fffffff; int bl = l; int bii = 0;
#pragma unroll
      for (int ii = 0; ii < 8; ++ii)
        if (lv[ii] > bv || (lv[ii] == bv && lh[ii] < bh)) { bv = lv[ii]; bh = lh[ii]; bii = ii; }
#pragma unroll
      for (int off = 32; off; off >>= 1) {
        float ov = __shfl_xor(bv, off, 64);
        int   oh = __shfl_xor(bh, off, 64);
        int   ol = __shfl_xor(bl, off, 64);
        int   oi = __shfl_xor(bii, off, 64);
        if (ov > bv || (ov == bv && oh < bh)) { bv = ov; bh = oh; bl = ol; bii = oi; }
      }
      if (l == 0) {
        if (bv > -0.5f) { sv[r] = bv; si[r] = bh; }
        else            { sv[r] = 0.f; si[r] = -1; }   // sentinel: no write collision
      }
#pragma unroll
      for (int ii = 0; ii < 8; ++ii)
        if (ii == bii && l == bl && bv > -0.5f) lv[ii] = -1.f;  // retire winner
    }
  }
  __syncthreads();

  // scatter exact top-32 into the zeroed z row (guarded: padding never writes)
  if (tid < NK) {
    int s = si[tid];
    if (s >= 0) zout[(size_t)b * NH + s] = sv[tid];
  }

  // sparse decode, float4: xhat[b,:] = b_dec + sum_j sv[j] * WdecT[si[j],:]
  if (tid < ND / 4) {                    // 192 active lanes
    float4 a = ((const float4*)b_dec)[tid];
#pragma unroll 8
    for (int j = 0; j < NK; ++j) {
      int hj = si[j]; hj = (hj < 0) ? 0 : hj;
      float vj = sv[j];                  // 0 for padding -> no contribution
      float4 wv = ((const float4*)(WdecT + (size_t)hj * ND))[tid];
      a.x = fmaf(vj, wv.x, a.x);
      a.y = fmaf(vj, wv.y, a.y);
      a.z = fmaf(vj, wv.z, a.z);
      a.w = fmaf(vj, wv.w, a.w);
    }
    ((float4*)(xhat + (size_t)b * ND))[tid] = a;
  }
}

// ---------------- launcher ----------------
extern "C" void kernel_launch(void* const* d_in, const int* in_sizes, int n_in,
                              void* d_out, int out_size, void* d_ws, size_t ws_size,
                              hipStream_t stream) {
  const float* x     = (const float*)d_in[0];
  const float* W_enc = (const float*)d_in[1];
  const float* b_enc = (const float*)d_in[2];
  const float* W_dec = (const float*)d_in[3];
  const float* b_dec = (const float*)d_in[4];

  float* xhat = (float*)d_out;
  float* zout = (float*)d_out + (size_t)NB * ND;       // final z (f32)
  unsigned short* za = (unsigned short*)zout;          // approx z (bf16) reuses z region

  char* ws = (char*)d_ws;
  unsigned short* x_bf    = (unsigned short*)(ws + OFF_XBF);
  unsigned short* wenc_bf = (unsigned short*)(ws + OFF_WENCB);
  float*          wdecT   = (float*)(ws + OFF_WDECT);
  int*            cidx    = (int*)(ws + OFF_CIDX);
  int*            ccnt    = (int*)(ws + OFF_CCNT);

  cast_bf16_kernel<<<1024, 256, 0, stream>>>(x, x_bf, NB * ND / 4);
  cast_bf16_kernel<<<2048, 256, 0, stream>>>(W_enc, wenc_bf, NH * ND / 4);
  transpose_kernel<<<dim3(NH / 32, ND / 32), dim3(32, 8), 0, stream>>>(W_dec, wdecT);
  encode_gemm_kernel<<<(NB / 128) * (NH / 128), 256, 0, stream>>>(x_bf, wenc_bf, b_enc, za);
  select_kernel<<<NB, 256, 0, stream>>>(za, cidx, ccnt);
  finalize_kernel<<<NB, 256, 0, stream>>>(x, W_enc, b_enc, cidx, ccnt, wdecT, b_dec, zout, xhat);
}

// Round 7
// 401.147 us; speedup vs baseline: 1.2612x; 1.1442x over previous
//
#include <hip/hip_runtime.h>

// K-Sparse Autoencoder fwd: B=4096, D=768, H=16384, K=32
// Determinism notes (tripwire discipline):
//  - no cross-call state: every ws/d_out byte read within a call is written earlier in that call
//  - candidate SET is deterministic (bisection+band are pure functions of data; CAND_MAX=512
//    >> worst-case ~110 so no truncation cliff)
//  - top-32 is order-independent (total order on (value desc, index asc)); padding uses si=-1
//  - all LDS write->read hand-offs are separated by __syncthreads() (full LDS fence)
//  - launcher branch depends only on ws_size (constant across calls) -> capture-safe
constexpr int NB = 4096;
constexpr int ND = 768;
constexpr int NH = 16384;
constexpr int NK = 32;
constexpr int CAND_MAX = 512;
#define DELTA 0.04f   // = 2*(6-sigma MFMA err 0.012 + bf16 store quant 0.0045)

typedef __bf16 bf16x8 __attribute__((ext_vector_type(8)));
typedef float  f32x4  __attribute__((ext_vector_type(4)));

// ---------------- workspace layout (bytes) ----------------
constexpr size_t OFF_XBF   = 0;                                     // x bf16      [NB][ND]
constexpr size_t OFF_WENCB = OFF_XBF   + (size_t)NB * ND * 2;       // W_enc bf16  [NH][ND]
constexpr size_t OFF_WDECT = OFF_WENCB + (size_t)NH * ND * 2;       // W_dec^T f32 [NH][ND]
constexpr size_t OFF_CIDX  = OFF_WDECT + (size_t)NH * ND * 4;       // cand_idx [NB][CAND_MAX] (fallback)
constexpr size_t OFF_CCNT  = OFF_CIDX  + (size_t)NB * CAND_MAX * 4; // cand_cnt [NB]           (fallback)
constexpr size_t OFF_ZA    = OFF_CCNT  + (size_t)NB * 4;            // za bf16 [NB][NH]        (fused)
constexpr size_t ZA_BYTES  = (size_t)NB * NH * 2;                   // 128 MB
// fused path requires ws_size >= OFF_ZA + ZA_BYTES (~224 MB); else za aliases zout (fallback)

__device__ inline unsigned short f2bf(float f) {
  unsigned u = __float_as_uint(f);
  unsigned r = u + 0x7fffu + ((u >> 16) & 1u);   // RNE
  return (unsigned short)(r >> 16);
}

__device__ __forceinline__ void gld_lds16(const unsigned short* g, unsigned short* s) {
  __builtin_amdgcn_global_load_lds((const __attribute__((address_space(1))) void*)g,
                                   (__attribute__((address_space(3))) void*)s, 16, 0, 0);
}

// ---------------- K1: f32 -> bf16 cast ----------------
__global__ __launch_bounds__(256) void cast_bf16_kernel(const float* __restrict__ in,
                                                        unsigned short* __restrict__ out,
                                                        int n4) {
  int stride = gridDim.x * 256;
  for (int i = blockIdx.x * 256 + threadIdx.x; i < n4; i += stride) {
    float4 v = ((const float4*)in)[i];
    unsigned long long p = (unsigned long long)f2bf(v.x)
                         | ((unsigned long long)f2bf(v.y) << 16)
                         | ((unsigned long long)f2bf(v.z) << 32)
                         | ((unsigned long long)f2bf(v.w) << 48);
    ((unsigned long long*)out)[i] = p;
  }
}

// ---------------- K2: transpose W_dec [ND][NH] -> [NH][ND] f32 ----------------
__global__ __launch_bounds__(256) void transpose_kernel(const float* __restrict__ in,
                                                        float* __restrict__ out) {
  __shared__ float tile[32][33];
  int hb = blockIdx.x * 32, db = blockIdx.y * 32;
  int tx = threadIdx.x, ty = threadIdx.y;   // 32 x 8
#pragma unroll
  for (int i = 0; i < 4; ++i)
    tile[ty + i * 8][tx] = in[(size_t)(db + ty + i * 8) * NH + hb + tx];
  __syncthreads();
#pragma unroll
  for (int i = 0; i < 4; ++i)
    out[(size_t)(hb + ty + i * 8) * ND + db + tx] = tile[tx][ty + i * 8];
}

// ---------------- K3: encode GEMM (bf16 MFMA) -> za bf16 (round-4 proven, unchanged) ----------------
__global__ __launch_bounds__(256) void encode_gemm_kernel(
    const unsigned short* __restrict__ Abf,   // [NB][ND]
    const unsigned short* __restrict__ Bbf,   // [NH][ND]
    const float* __restrict__ b_enc,
    unsigned short* __restrict__ za) {        // [NB][NH] bf16
  __shared__ __align__(16) unsigned short As[128 * 64];
  __shared__ __align__(16) unsigned short Bs[128 * 64];

  // super-tile mapping (bijective): per XCD, 8bm x 8bn chunks -> A+B slices L2-resident
  int bid = blockIdx.x;
  int x  = bid & 7;
  int j  = bid >> 3;
  int st = j >> 6;
  int w  = j & 63;
  int g  = st * 8 + x;
  int bm = (g & 3) * 8 + (w & 7);
  int bn = (g >> 2) * 8 + (w >> 3);
  int m0 = bm * 128, n0 = bn * 128;

  int tid = threadIdx.x, wid = tid >> 6, l = tid & 63;
  int wr = wid >> 1, wc = wid & 1;
  int lr = l & 15, lk = l >> 4;

  int srow = l >> 3;
  int scol = (l & 7) ^ srow;            // pre-swizzled global source (rule #21)

  f32x4 acc[4][4] = {};

  for (int kt = 0; kt < 12; ++kt) {
    __syncthreads();
#pragma unroll
    for (int t = 0; t < 4; ++t) {
      int c = wid * 4 + t;
      gld_lds16(Abf + ((size_t)(m0 + c * 8 + srow) * ND + kt * 64 + scol * 8), &As[c * 512]);
      gld_lds16(Bbf + ((size_t)(n0 + c * 8 + srow) * ND + kt * 64 + scol * 8), &Bs[c * 512]);
    }
    asm volatile("s_waitcnt vmcnt(0)" ::: "memory");
    __syncthreads();
#pragma unroll
    for (int kk = 0; kk < 2; ++kk) {
      bf16x8 af[4], bq[4];
      int u = (kk * 4 + lk) ^ (lr & 7);
#pragma unroll
      for (int i = 0; i < 4; ++i)
        af[i] = *(const bf16x8*)&As[(wr * 64 + i * 16 + lr) * 64 + u * 8];
#pragma unroll
      for (int j2 = 0; j2 < 4; ++j2)
        bq[j2] = *(const bf16x8*)&Bs[(wc * 64 + j2 * 16 + lr) * 64 + u * 8];
#pragma unroll
      for (int i = 0; i < 4; ++i)
#pragma unroll
        for (int j2 = 0; j2 < 4; ++j2)
          acc[i][j2] = __builtin_amdgcn_mfma_f32_16x16x32_bf16(af[i], bq[j2], acc[i][j2], 0, 0, 0);
    }
  }

  __syncthreads();
  unsigned short* ep = (wid < 2) ? &As[wid * 4096] : &Bs[(wid - 2) * 4096];
#pragma unroll
  for (int j2 = 0; j2 < 4; ++j2) {
    float bias = b_enc[n0 + wc * 64 + j2 * 16 + lr];
#pragma unroll
    for (int i = 0; i < 4; ++i) {
#pragma unroll
      for (int q = 0; q < 4; ++q) {
        int row = i * 16 + lk * 4 + q;
        int col = j2 * 16 + lr;
        float v = fmaxf(acc[i][j2][q] + bias, 0.0f);
        ep[row * 64 + (((col >> 3) ^ (row & 7)) * 8) + (col & 7)] = f2bf(v);
      }
    }
  }
  __syncthreads();
#pragma unroll
  for (int t = 0; t < 8; ++t) {
    int row = t * 8 + (l >> 3);
    int u = (l & 7) ^ (row & 7);
    int4 d = *(const int4*)&ep[row * 64 + u * 8];
    *(int4*)(za + (size_t)(m0 + wr * 64 + row) * NH + n0 + wc * 64 + (l & 7) * 8) = d;
  }
}

// ======== shared device helpers for select/finalize phases ========

// bisection on 8x uint4 of bf16 (v), returns thr (f32). Uniform result across block.
__device__ __forceinline__ float bisect_thr(const uint4* v, int* wcnt, int tid) {
  unsigned lo = 0u, hi = 0x7F80u;
  for (int it = 0; it < 15; ++it) {
    unsigned mid = (lo + hi) >> 1;
    int c = 0;
#pragma unroll
    for (int i = 0; i < 8; ++i) {
      const unsigned* p = (const unsigned*)&v[i];
#pragma unroll
      for (int e = 0; e < 4; ++e) {
        unsigned u = p[e];
        c += ((u & 0xFFFFu) >= mid) ? 1 : 0;
        c += ((u >> 16) >= mid) ? 1 : 0;
      }
    }
#pragma unroll
    for (int off = 32; off; off >>= 1) c += __shfl_xor(c, off, 64);
    if ((tid & 63) == 0) wcnt[tid >> 6] = c;
    __syncthreads();
    int tot = wcnt[0] + wcnt[1] + wcnt[2] + wcnt[3];
    __syncthreads();
    if (tot >= NK) {
      lo = mid;
      if (tot <= 48) break;           // deterministic band: 32 <= count <= 48
    } else {
      hi = mid;
    }
  }
  float thr = __uint_as_float(lo << 16) - DELTA;
  return (thr < 1e-12f) ? 1e-12f : thr;
}

// wave-0 top-32 over (cv,ci)[0..cnt) by (value desc, index asc); writes sv/si (si=-1 pad)
__device__ __forceinline__ void topk_wave0(const float* cv, const int* ci, int cnt,
                                           float* sv, int* si, int l) {
  float lv[8]; int lh[8];
#pragma unroll
  for (int ii = 0; ii < 8; ++ii) {
    int c = l + 64 * ii;
    if (c < cnt) { lv[ii] = cv[c]; lh[ii] = ci[c]; }
    else         { lv[ii] = -1.f;  lh[ii] = 0x7fffffff; }
  }
  for (int r = 0; r < NK; ++r) {
    float bv = -1.f; int bh = 0x7fffffff; int bl = l; int bii = 0;
#pragma unroll
    for (int ii = 0; ii < 8; ++ii)
      if (lv[ii] > bv || (lv[ii] == bv && lh[ii] < bh)) { bv = lv[ii]; bh = lh[ii]; bii = ii; }
#pragma unroll
    for (int off = 32; off; off >>= 1) {
      float ov = __shfl_xor(bv, off, 64);
      int   oh = __shfl_xor(bh, off, 64);
      int   ol = __shfl_xor(bl, off, 64);
      int   oi = __shfl_xor(bii, off, 64);
      if (ov > bv || (ov == bv && oh < bh)) { bv = ov; bh = oh; bl = ol; bii = oi; }
    }
    if (l == 0) {
      if (bv > -0.5f) { sv[r] = bv; si[r] = bh; }
      else            { sv[r] = 0.f; si[r] = -1; }
    }
#pragma unroll
    for (int ii = 0; ii < 8; ++ii)
      if (ii == bii && l == bl && bv > -0.5f) lv[ii] = -1.f;
  }
}

// ---------------- K4 (fallback): select ----------------
__global__ __launch_bounds__(256) void select_kernel(const unsigned short* __restrict__ za,
                                                     int* __restrict__ cand_idx,
                                                     int* __restrict__ cand_cnt) {
  int b = blockIdx.x, tid = threadIdx.x;
  const uint4* zrow = (const uint4*)(za + (size_t)b * NH);
  uint4 v[8];
#pragma unroll
  for (int i = 0; i < 8; ++i) v[i] = zrow[tid + 256 * i];

  __shared__ int wcnt[4];
  __shared__ int lcnt;
  float thr = bisect_thr(v, wcnt, tid);
  if (tid == 0) lcnt = 0;
  __syncthreads();
#pragma unroll
  for (int i = 0; i < 8; ++i) {
    const unsigned* p = (const unsigned*)&v[i];
#pragma unroll
    for (int e = 0; e < 4; ++e) {
      unsigned u = p[e];
      int hbase = (tid + 256 * i) * 8 + e * 2;
      float f0 = __uint_as_float((u & 0xFFFFu) << 16);
      float f1 = __uint_as_float(u & 0xFFFF0000u);
      if (f0 >= thr) { int s = atomicAdd(&lcnt, 1); if (s < CAND_MAX) cand_idx[(size_t)b * CAND_MAX + s] = hbase; }
      if (f1 >= thr) { int s = atomicAdd(&lcnt, 1); if (s < CAND_MAX) cand_idx[(size_t)b * CAND_MAX + s] = hbase + 1; }
    }
  }
  __syncthreads();
  if (tid == 0) cand_cnt[b] = (lcnt < CAND_MAX) ? lcnt : CAND_MAX;
}

// ======== finalize core: gather + topk(wave0) || zero(waves1-3) + scatter + decode ========
__device__ __forceinline__ void finalize_core(
    int b, int tid, int wid, int l, int cnt,
    const float* __restrict__ W_enc, const float* __restrict__ b_enc,
    const float* __restrict__ WdecT, const float* __restrict__ b_dec,
    const float* xr, float* cv, const int* ci, float* sv, int* si,
    float* __restrict__ zout, float* __restrict__ xhat) {
  // exact f32 dot per candidate, one wave each, float4-vectorized
  const float4* xr4 = (const float4*)xr;
  for (int c = wid; c < cnt; c += 4) {
    int h = ci[c];
    const float4* wrow4 = (const float4*)(W_enc + (size_t)h * ND);
    float4 s4 = make_float4(0.f, 0.f, 0.f, 0.f);
#pragma unroll
    for (int i = 0; i < 3; ++i) {
      float4 wv = wrow4[l + 64 * i];
      float4 xv = xr4[l + 64 * i];
      s4.x = fmaf(wv.x, xv.x, s4.x);
      s4.y = fmaf(wv.y, xv.y, s4.y);
      s4.z = fmaf(wv.z, xv.z, s4.z);
      s4.w = fmaf(wv.w, xv.w, s4.w);
    }
    float s = (s4.x + s4.y) + (s4.z + s4.w);
#pragma unroll
    for (int off = 32; off; off >>= 1) s += __shfl_xor(s, off, 64);
    if (l == 0) cv[c] = fmaxf(s + b_enc[h], 0.f);
  }
  __syncthreads();

  // wave 0: top-32; waves 1-3: zero the z row (post-gather: no L3 pollution during gathers)
  if (wid == 0) {
    topk_wave0(cv, ci, cnt, sv, si, l);
  } else {
    float4 z4 = make_float4(0.f, 0.f, 0.f, 0.f);
    float4* zr = (float4*)(zout + (size_t)b * NH);
    for (int i = tid - 64; i < NH / 4; i += 192) zr[i] = z4;
  }
  __syncthreads();

  // scatter exact top-32 (guarded: padding never writes)
  if (tid < NK) {
    int s = si[tid];
    if (s >= 0) zout[(size_t)b * NH + s] = sv[tid];
  }

  // sparse decode, float4
  if (tid < ND / 4) {
    float4 a = ((const float4*)b_dec)[tid];
#pragma unroll 8
    for (int j = 0; j < NK; ++j) {
      int hj = si[j]; hj = (hj < 0) ? 0 : hj;
      float vj = sv[j];
      float4 wv = ((const float4*)(WdecT + (size_t)hj * ND))[tid];
      a.x = fmaf(vj, wv.x, a.x);
      a.y = fmaf(vj, wv.y, a.y);
      a.z = fmaf(vj, wv.z, a.z);
      a.w = fmaf(vj, wv.w, a.w);
    }
    ((float4*)(xhat + (size_t)b * ND))[tid] = a;
  }
}

// ---------------- K5 (fallback): finalize from cidx/ccnt ----------------
__global__ __launch_bounds__(256) void finalize_kernel(
    const float* __restrict__ x, const float* __restrict__ W_enc,
    const float* __restrict__ b_enc,
    const int* __restrict__ cand_idx, const int* __restrict__ cand_cnt,
    const float* __restrict__ WdecT, const float* __restrict__ b_dec,
    float* __restrict__ zout, float* __restrict__ xhat) {
  int b = blockIdx.x, tid = threadIdx.x;
  int wid = tid >> 6, l = tid & 63;
  __shared__ __align__(16) float xr[ND];
  __shared__ float cv[CAND_MAX];
  __shared__ int   ci[CAND_MAX];
  __shared__ float sv[NK];
  __shared__ int   si[NK];

  int cnt = cand_cnt[b];
  const float4* xrow = (const float4*)(x + (size_t)b * ND);
  for (int i = tid; i < ND / 4; i += 256) ((float4*)xr)[i] = xrow[i];
  for (int c = tid; c < cnt; c += 256) ci[c] = cand_idx[(size_t)b * CAND_MAX + c];
  __syncthreads();
  finalize_core(b, tid, wid, l, cnt, W_enc, b_enc, WdecT, b_dec,
                xr, cv, ci, sv, si, zout, xhat);
}

// ---------------- K4+K5 (fused, za in ws): select+finalize in one dispatch ----------------
__global__ __launch_bounds__(256) void fused_finalize_kernel(
    const unsigned short* __restrict__ za,
    const float* __restrict__ x, const float* __restrict__ W_enc,
    const float* __restrict__ b_enc,
    const float* __restrict__ WdecT, const float* __restrict__ b_dec,
    float* __restrict__ zout, float* __restrict__ xhat) {
  int b = blockIdx.x, tid = threadIdx.x;
  int wid = tid >> 6, l = tid & 63;
  __shared__ __align__(16) float xr[ND];
  __shared__ float cv[CAND_MAX];
  __shared__ int   ci[CAND_MAX];
  __shared__ float sv[NK];
  __shared__ int   si[NK];
  __shared__ int   wcnt[4];
  __shared__ int   lcnt;

  // za row -> registers; x row -> LDS (loads overlap)
  const uint4* zrow = (const uint4*)(za + (size_t)b * NH);
  uint4 v[8];
#pragma unroll
  for (int i = 0; i < 8; ++i) v[i] = zrow[tid + 256 * i];
  const float4* xrow = (const float4*)(x + (size_t)b * ND);
  for (int i = tid; i < ND / 4; i += 256) ((float4*)xr)[i] = xrow[i];

  float thr = bisect_thr(v, wcnt, tid);   // contains barriers (covers xr writes too)
  if (tid == 0) lcnt = 0;
  __syncthreads();
#pragma unroll
  for (int i = 0; i < 8; ++i) {
    const unsigned* p = (const unsigned*)&v[i];
#pragma unroll
    for (int e = 0; e < 4; ++e) {
      unsigned u = p[e];
      int hbase = (tid + 256 * i) * 8 + e * 2;
      float f0 = __uint_as_float((u & 0xFFFFu) << 16);
      float f1 = __uint_as_float(u & 0xFFFF0000u);
      if (f0 >= thr) { int s = atomicAdd(&lcnt, 1); if (s < CAND_MAX) ci[s] = hbase; }
      if (f1 >= thr) { int s = atomicAdd(&lcnt, 1); if (s < CAND_MAX) ci[s] = hbase + 1; }
    }
  }
  __syncthreads();
  int cnt = (lcnt < CAND_MAX) ? lcnt : CAND_MAX;

  finalize_core(b, tid, wid, l, cnt, W_enc, b_enc, WdecT, b_dec,
                xr, cv, ci, sv, si, zout, xhat);
}

// ---------------- launcher ----------------
extern "C" void kernel_launch(void* const* d_in, const int* in_sizes, int n_in,
                              void* d_out, int out_size, void* d_ws, size_t ws_size,
                              hipStream_t stream) {
  const float* x     = (const float*)d_in[0];
  const float* W_enc = (const float*)d_in[1];
  const float* b_enc = (const float*)d_in[2];
  const float* W_dec = (const float*)d_in[3];
  const float* b_dec = (const float*)d_in[4];

  float* xhat = (float*)d_out;
  float* zout = (float*)d_out + (size_t)NB * ND;

  char* ws = (char*)d_ws;
  unsigned short* x_bf    = (unsigned short*)(ws + OFF_XBF);
  unsigned short* wenc_bf = (unsigned short*)(ws + OFF_WENCB);
  float*          wdecT   = (float*)(ws + OFF_WDECT);
  int*            cidx    = (int*)(ws + OFF_CIDX);
  int*            ccnt    = (int*)(ws + OFF_CCNT);

  bool fused = ws_size >= OFF_ZA + ZA_BYTES;   // constant across calls -> capture-safe
  unsigned short* za = fused ? (unsigned short*)(ws + OFF_ZA)
                             : (unsigned short*)zout;   // fallback: za aliases z region

  cast_bf16_kernel<<<1024, 256, 0, stream>>>(x, x_bf, NB * ND / 4);
  cast_bf16_kernel<<<2048, 256, 0, stream>>>(W_enc, wenc_bf, NH * ND / 4);
  transpose_kernel<<<dim3(NH / 32, ND / 32), dim3(32, 8), 0, stream>>>(W_dec, wdecT);
  encode_gemm_kernel<<<(NB / 128) * (NH / 128), 256, 0, stream>>>(x_bf, wenc_bf, b_enc, za);
  if (fused) {
    fused_finalize_kernel<<<NB, 256, 0, stream>>>(za, x, W_enc, b_enc, wdecT, b_dec, zout, xhat);
  } else {
    select_kernel<<<NB, 256, 0, stream>>>(za, cidx, ccnt);
    finalize_kernel<<<NB, 256, 0, stream>>>(x, W_enc, b_enc, cidx, ccnt, wdecT, b_dec, zout, xhat);
  }
}

// Round 8
// 358.282 us; speedup vs baseline: 1.4121x; 1.1196x over previous
//
#include <hip/hip_runtime.h>

// K-Sparse Autoencoder fwd: B=4096, D=768, H=16384, K=32
// Determinism notes (tripwire discipline):
//  - no cross-call state: every ws/d_out byte read within a call is written earlier in that call
//  - candidate SET is deterministic (bisection+band pure functions of data; CAND_MAX=512)
//  - top-32 is order-independent (total order on (value desc, index asc)); padding si=-1
//  - GEMM pipeline: all barriers/waits wave-uniform; stage target buffer (kt+2)%3 is provably
//    dead (its readers finished before the kt-1 -> kt boundary barrier); vmcnt counted per-wave
constexpr int NB = 4096;
constexpr int ND = 768;
constexpr int NH = 16384;
constexpr int NK = 32;
constexpr int CAND_MAX = 512;
#define DELTA 0.04f   // = 2*(6-sigma MFMA err 0.012 + bf16 store quant 0.0045)

typedef __bf16 bf16x8 __attribute__((ext_vector_type(8)));
typedef float  f32x4  __attribute__((ext_vector_type(4)));

// ---------------- workspace layout (bytes) ----------------
constexpr size_t OFF_XBF   = 0;                                     // x bf16      [NB][ND]
constexpr size_t OFF_WENCB = OFF_XBF   + (size_t)NB * ND * 2;       // W_enc bf16  [NH][ND]
constexpr size_t OFF_WDECT = OFF_WENCB + (size_t)NH * ND * 2;       // W_dec^T f32 [NH][ND]
constexpr size_t OFF_CIDX  = OFF_WDECT + (size_t)NH * ND * 4;       // cand_idx (fallback)
constexpr size_t OFF_CCNT  = OFF_CIDX  + (size_t)NB * CAND_MAX * 4; // cand_cnt (fallback)
constexpr size_t OFF_ZA    = OFF_CCNT  + (size_t)NB * 4;            // za bf16 [NB][NH] (fused)
constexpr size_t ZA_BYTES  = (size_t)NB * NH * 2;

__device__ inline unsigned short f2bf(float f) {
  unsigned u = __float_as_uint(f);
  unsigned r = u + 0x7fffu + ((u >> 16) & 1u);   // RNE
  return (unsigned short)(r >> 16);
}

__device__ __forceinline__ void gld_lds16(const unsigned short* g, unsigned short* s) {
  // async global->LDS, 16B/lane; LDS dest = wave-uniform base + lane*16 (HW rule)
  __builtin_amdgcn_global_load_lds((const __attribute__((address_space(1))) void*)g,
                                   (__attribute__((address_space(3))) void*)s, 16, 0, 0);
}

// ---------------- K1: f32 -> bf16 cast ----------------
__global__ __launch_bounds__(256) void cast_bf16_kernel(const float* __restrict__ in,
                                                        unsigned short* __restrict__ out,
                                                        int n4) {
  int stride = gridDim.x * 256;
  for (int i = blockIdx.x * 256 + threadIdx.x; i < n4; i += stride) {
    float4 v = ((const float4*)in)[i];
    unsigned long long p = (unsigned long long)f2bf(v.x)
                         | ((unsigned long long)f2bf(v.y) << 16)
                         | ((unsigned long long)f2bf(v.z) << 32)
                         | ((unsigned long long)f2bf(v.w) << 48);
    ((unsigned long long*)out)[i] = p;
  }
}

// ---------------- K2: transpose W_dec [ND][NH] -> [NH][ND] f32 ----------------
__global__ __launch_bounds__(256) void transpose_kernel(const float* __restrict__ in,
                                                        float* __restrict__ out) {
  __shared__ float tile[32][33];
  int hb = blockIdx.x * 32, db = blockIdx.y * 32;
  int tx = threadIdx.x, ty = threadIdx.y;   // 32 x 8
#pragma unroll
  for (int i = 0; i < 4; ++i)
    tile[ty + i * 8][tx] = in[(size_t)(db + ty + i * 8) * NH + hb + tx];
  __syncthreads();
#pragma unroll
  for (int i = 0; i < 4; ++i)
    out[(size_t)(hb + ty + i * 8) * ND + db + tx] = tile[tx][ty + i * 8];
}

// ---------------- K3: encode GEMM 256x256, BK=32, 8 waves, 3-buffer pipeline ----------------
// za = relu(x_bf @ W_enc_bf^T + b_enc) -> bf16. Per K-tile: 2 phases of
// {ds_read frags || issue gld_lds(kt+2) -> setprio(1) 16 MFMA setprio(0)}; one raw
// s_barrier + counted vmcnt(4) per tile (counted: kt+2's loads stay in flight).
__global__ __launch_bounds__(512) void encode_gemm_kernel(
    const unsigned short* __restrict__ Abf,   // [NB][ND]
    const unsigned short* __restrict__ Bbf,   // [NH][ND]
    const float* __restrict__ b_enc,
    unsigned short* __restrict__ za) {        // [NB][NH] bf16
  __shared__ __align__(16) unsigned short lds_all[3 * 16384];   // 96 KB: 3 bufs x (A 16K + B 16K)

  // super-tile mapping (bijective): 1024 blocks; per XCD 4bm x 4bn chunks (A+B slices ~3MB L2)
  int bid = blockIdx.x;                 // 0..1023
  int xx = bid & 7;                     // XCD
  int jj = bid >> 3;                    // 0..127
  int st = jj >> 4;                     // 0..7
  int w  = jj & 15;                     // 0..15
  int g  = st * 8 + xx;                 // 0..63 (4 sm x 16 sn)
  int bm = (g & 3) * 4 + (w & 3);       // 0..15
  int bn = (g >> 2) * 4 + (w >> 2);     // 0..63
  int m0 = bm * 256, n0 = bn * 256;

  int tid = threadIdx.x;                // 0..511
  int wid = tid >> 6, l = tid & 63;
  int wr = wid >> 2, wc = wid & 3;      // 2 M-waves x 4 N-waves
  int lr = l & 15, lk = l >> 4;

#define STAGE_A(nbuf, ktile, t) do {                                              \
    int c_ = (t) * 512 + tid; int r_ = c_ >> 2;                                   \
    int lu_ = (c_ & 3) ^ ((r_ >> 1) & 3);                                         \
    gld_lds16(Abf + (size_t)(m0 + r_) * ND + (ktile) * 32 + lu_ * 8,              \
              lds_all + (nbuf) * 16384 + ((t) * 512 + (wid << 6)) * 8);           \
  } while (0)
#define STAGE_B(nbuf, ktile, t) do {                                              \
    int c_ = (t) * 512 + tid; int r_ = c_ >> 2;                                   \
    int lu_ = (c_ & 3) ^ ((r_ >> 1) & 3);                                         \
    gld_lds16(Bbf + (size_t)(n0 + r_) * ND + (ktile) * 32 + lu_ * 8,              \
              lds_all + (nbuf) * 16384 + 8192 + ((t) * 512 + (wid << 6)) * 8);    \
  } while (0)

  f32x4 acc[8][4] = {};

  // prologue: stage kt=0 -> buf0, kt=1 -> buf1 (8 loads/thread total)
  STAGE_A(0, 0, 0); STAGE_A(0, 0, 1); STAGE_B(0, 0, 0); STAGE_B(0, 0, 1);
  STAGE_A(1, 1, 0); STAGE_A(1, 1, 1); STAGE_B(1, 1, 0); STAGE_B(1, 1, 1);
  asm volatile("s_waitcnt vmcnt(4)" ::: "memory");   // kt0 resident; kt1 in flight
  __builtin_amdgcn_s_barrier();
  __builtin_amdgcn_sched_barrier(0);

  int cur = 0;
  for (int kt = 0; kt < 24; ++kt) {     // ND/32
    int nx = cur + 2; if (nx >= 3) nx -= 3;          // (kt+2)%3 — provably dead buffer
    const unsigned short* Ab = lds_all + cur * 16384;
    const unsigned short* Bb = Ab + 8192;
    bf16x8 aF[4], bF[4];

    // ---- phase 1: B frags (4) + A frags fi0..3 (4) | stage A(kt+2) | MFMA 16 ----
#pragma unroll
    for (int fj = 0; fj < 4; ++fj) {
      int row = wc * 64 + fj * 16 + lr;
      int pu = lk ^ ((row >> 1) & 3);
      bF[fj] = *(const bf16x8*)(Bb + row * 32 + pu * 8);
    }
#pragma unroll
    for (int fi = 0; fi < 4; ++fi) {
      int row = wr * 128 + fi * 16 + lr;
      int pu = lk ^ ((row >> 1) & 3);
      aF[fi] = *(const bf16x8*)(Ab + row * 32 + pu * 8);
    }
    if (kt < 22) { STAGE_A(nx, kt + 2, 0); STAGE_A(nx, kt + 2, 1); }
    __builtin_amdgcn_s_setprio(1);
#pragma unroll
    for (int fi = 0; fi < 4; ++fi)
#pragma unroll
      for (int fj = 0; fj < 4; ++fj)
        acc[fi][fj] = __builtin_amdgcn_mfma_f32_16x16x32_bf16(aF[fi], bF[fj], acc[fi][fj], 0, 0, 0);
    __builtin_amdgcn_s_setprio(0);

    // ---- phase 2: A frags fi4..7 (4) | stage B(kt+2) | MFMA 16 (reuse bF) ----
#pragma unroll
    for (int fi = 0; fi < 4; ++fi) {
      int row = wr * 128 + (4 + fi) * 16 + lr;
      int pu = lk ^ ((row >> 1) & 3);
      aF[fi] = *(const bf16x8*)(Ab + row * 32 + pu * 8);
    }
    if (kt < 22) { STAGE_B(nx, kt + 2, 0); STAGE_B(nx, kt + 2, 1); }
    __builtin_amdgcn_s_setprio(1);
#pragma unroll
    for (int fi = 0; fi < 4; ++fi)
#pragma unroll
      for (int fj = 0; fj < 4; ++fj)
        acc[4 + fi][fj] = __builtin_amdgcn_mfma_f32_16x16x32_bf16(aF[fi], bF[fj], acc[4 + fi][fj], 0, 0, 0);
    __builtin_amdgcn_s_setprio(0);

    // ---- tile boundary: counted wait (kt+1 resident, kt+2 stays in flight) ----
    if (kt < 23) {
      if (kt == 22) asm volatile("s_waitcnt vmcnt(0)" ::: "memory");  // tail: kt23 must land
      else          asm volatile("s_waitcnt vmcnt(4)" ::: "memory");
      __builtin_amdgcn_s_barrier();
      __builtin_amdgcn_sched_barrier(0);
    }
    cur = (cur == 2) ? 0 : cur + 1;
  }
#undef STAGE_A
#undef STAGE_B

  // ---- epilogue: bias+relu -> bf16 via LDS (two 64-row passes), coalesced 16B stores ----
  __syncthreads();                      // full fence; all pipeline loads long consumed
  unsigned short* ep = lds_all + wid * 4096;   // [64][64] bf16 per wave (8 x 8KB = 64KB)
#pragma unroll
  for (int half = 0; half < 2; ++half) {
#pragma unroll
    for (int fj = 0; fj < 4; ++fj) {
      float bias = b_enc[n0 + wc * 64 + fj * 16 + lr];
#pragma unroll
      for (int i2 = 0; i2 < 4; ++i2) {
#pragma unroll
        for (int q = 0; q < 4; ++q) {
          int row = i2 * 16 + lk * 4 + q;     // 0..63 (C/D: row=(l>>4)*4+q)
          int col = fj * 16 + lr;             // 0..63 (col=l&15)
          float v = fmaxf(acc[half * 4 + i2][fj][q] + bias, 0.0f);
          ep[row * 64 + (((col >> 3) ^ (row & 7)) * 8) + (col & 7)] = f2bf(v);
        }
      }
    }
    __syncthreads();                    // FENCE: ep writes visible
#pragma unroll
    for (int t = 0; t < 8; ++t) {
      int row = t * 8 + (l >> 3);
      int u = (l & 7) ^ (row & 7);
      int4 d = *(const int4*)&ep[row * 64 + u * 8];
      *(int4*)(za + (size_t)(m0 + wr * 128 + half * 64 + row) * NH
                    + n0 + wc * 64 + (l & 7) * 8) = d;
    }
    __syncthreads();                    // before next half overwrites ep
  }
}

// ======== shared device helpers for select/finalize phases ========

__device__ __forceinline__ float bisect_thr(const uint4* v, int* wcnt, int tid) {
  unsigned lo = 0u, hi = 0x7F80u;
  for (int it = 0; it < 15; ++it) {
    unsigned mid = (lo + hi) >> 1;
    int c = 0;
#pragma unroll
    for (int i = 0; i < 8; ++i) {
      const unsigned* p = (const unsigned*)&v[i];
#pragma unroll
      for (int e = 0; e < 4; ++e) {
        unsigned u = p[e];
        c += ((u & 0xFFFFu) >= mid) ? 1 : 0;
        c += ((u >> 16) >= mid) ? 1 : 0;
      }
    }
#pragma unroll
    for (int off = 32; off; off >>= 1) c += __shfl_xor(c, off, 64);
    if ((tid & 63) == 0) wcnt[tid >> 6] = c;
    __syncthreads();
    int tot = wcnt[0] + wcnt[1] + wcnt[2] + wcnt[3];
    __syncthreads();
    if (tot >= NK) {
      lo = mid;
      if (tot <= 48) break;           // deterministic band: 32 <= count <= 48
    } else {
      hi = mid;
    }
  }
  float thr = __uint_as_float(lo << 16) - DELTA;
  return (thr < 1e-12f) ? 1e-12f : thr;
}

__device__ __forceinline__ void topk_wave0(const float* cv, const int* ci, int cnt,
                                           float* sv, int* si, int l) {
  float lv[8]; int lh[8];
#pragma unroll
  for (int ii = 0; ii < 8; ++ii) {
    int c = l + 64 * ii;
    if (c < cnt) { lv[ii] = cv[c]; lh[ii] = ci[c]; }
    else         { lv[ii] = -1.f;  lh[ii] = 0x7fffffff; }
  }
  for (int r = 0; r < NK; ++r) {
    float bv = -1.f; int bh = 0x7fffffff; int bl = l; int bii = 0;
#pragma unroll
    for (int ii = 0; ii < 8; ++ii)
      if (lv[ii] > bv || (lv[ii] == bv && lh[ii] < bh)) { bv = lv[ii]; bh = lh[ii]; bii = ii; }
#pragma unroll
    for (int off = 32; off; off >>= 1) {
      float ov = __shfl_xor(bv, off, 64);
      int   oh = __shfl_xor(bh, off, 64);
      int   ol = __shfl_xor(bl, off, 64);
      int   oi = __shfl_xor(bii, off, 64);
      if (ov > bv || (ov == bv && oh < bh)) { bv = ov; bh = oh; bl = ol; bii = oi; }
    }
    if (l == 0) {
      if (bv > -0.5f) { sv[r] = bv; si[r] = bh; }
      else            { sv[r] = 0.f; si[r] = -1; }
    }
#pragma unroll
    for (int ii = 0; ii < 8; ++ii)
      if (ii == bii && l == bl && bv > -0.5f) lv[ii] = -1.f;
  }
}

// ---------------- K4 (fallback): select ----------------
__global__ __launch_bounds__(256) void select_kernel(const unsigned short* __restrict__ za,
                                                     int* __restrict__ cand_idx,
                                                     int* __restrict__ cand_cnt) {
  int b = blockIdx.x, tid = threadIdx.x;
  const uint4* zrow = (const uint4*)(za + (size_t)b * NH);
  uint4 v[8];
#pragma unroll
  for (int i = 0; i < 8; ++i) v[i] = zrow[tid + 256 * i];

  __shared__ int wcnt[4];
  __shared__ int lcnt;
  float thr = bisect_thr(v, wcnt, tid);
  if (tid == 0) lcnt = 0;
  __syncthreads();
#pragma unroll
  for (int i = 0; i < 8; ++i) {
    const unsigned* p = (const unsigned*)&v[i];
#pragma unroll
    for (int e = 0; e < 4; ++e) {
      unsigned u = p[e];
      int hbase = (tid + 256 * i) * 8 + e * 2;
      float f0 = __uint_as_float((u & 0xFFFFu) << 16);
      float f1 = __uint_as_float(u & 0xFFFF0000u);
      if (f0 >= thr) { int s = atomicAdd(&lcnt, 1); if (s < CAND_MAX) cand_idx[(size_t)b * CAND_MAX + s] = hbase; }
      if (f1 >= thr) { int s = atomicAdd(&lcnt, 1); if (s < CAND_MAX) cand_idx[(size_t)b * CAND_MAX + s] = hbase + 1; }
    }
  }
  __syncthreads();
  if (tid == 0) cand_cnt[b] = (lcnt < CAND_MAX) ? lcnt : CAND_MAX;
}

// ======== finalize core ========
__device__ __forceinline__ void finalize_core(
    int b, int tid, int wid, int l, int cnt,
    const float* __restrict__ W_enc, const float* __restrict__ b_enc,
    const float* __restrict__ WdecT, const float* __restrict__ b_dec,
    const float* xr, float* cv, const int* ci, float* sv, int* si,
    float* __restrict__ zout, float* __restrict__ xhat) {
  const float4* xr4 = (const float4*)xr;
  for (int c = wid; c < cnt; c += 4) {
    int h = ci[c];
    const float4* wrow4 = (const float4*)(W_enc + (size_t)h * ND);
    float4 s4 = make_float4(0.f, 0.f, 0.f, 0.f);
#pragma unroll
    for (int i = 0; i < 3; ++i) {
      float4 wv = wrow4[l + 64 * i];
      float4 xv = xr4[l + 64 * i];
      s4.x = fmaf(wv.x, xv.x, s4.x);
      s4.y = fmaf(wv.y, xv.y, s4.y);
      s4.z = fmaf(wv.z, xv.z, s4.z);
      s4.w = fmaf(wv.w, xv.w, s4.w);
    }
    float s = (s4.x + s4.y) + (s4.z + s4.w);
#pragma unroll
    for (int off = 32; off; off >>= 1) s += __shfl_xor(s, off, 64);
    if (l == 0) cv[c] = fmaxf(s + b_enc[h], 0.f);
  }
  __syncthreads();

  if (wid == 0) {
    topk_wave0(cv, ci, cnt, sv, si, l);
  } else {
    float4 z4 = make_float4(0.f, 0.f, 0.f, 0.f);
    float4* zr = (float4*)(zout + (size_t)b * NH);
    for (int i = tid - 64; i < NH / 4; i += 192) zr[i] = z4;
  }
  __syncthreads();

  if (tid < NK) {
    int s = si[tid];
    if (s >= 0) zout[(size_t)b * NH + s] = sv[tid];
  }

  if (tid < ND / 4) {
    float4 a = ((const float4*)b_dec)[tid];
#pragma unroll 8
    for (int j = 0; j < NK; ++j) {
      int hj = si[j]; hj = (hj < 0) ? 0 : hj;
      float vj = sv[j];
      float4 wv = ((const float4*)(WdecT + (size_t)hj * ND))[tid];
      a.x = fmaf(vj, wv.x, a.x);
      a.y = fmaf(vj, wv.y, a.y);
      a.z = fmaf(vj, wv.z, a.z);
      a.w = fmaf(vj, wv.w, a.w);
    }
    ((float4*)(xhat + (size_t)b * ND))[tid] = a;
  }
}

// ---------------- K5 (fallback): finalize from cidx/ccnt ----------------
__global__ __launch_bounds__(256) void finalize_kernel(
    const float* __restrict__ x, const float* __restrict__ W_enc,
    const float* __restrict__ b_enc,
    const int* __restrict__ cand_idx, const int* __restrict__ cand_cnt,
    const float* __restrict__ WdecT, const float* __restrict__ b_dec,
    float* __restrict__ zout, float* __restrict__ xhat) {
  int b = blockIdx.x, tid = threadIdx.x;
  int wid = tid >> 6, l = tid & 63;
  __shared__ __align__(16) float xr[ND];
  __shared__ float cv[CAND_MAX];
  __shared__ int   ci[CAND_MAX];
  __shared__ float sv[NK];
  __shared__ int   si[NK];

  int cnt = cand_cnt[b];
  const float4* xrow = (const float4*)(x + (size_t)b * ND);
  for (int i = tid; i < ND / 4; i += 256) ((float4*)xr)[i] = xrow[i];
  for (int c = tid; c < cnt; c += 256) ci[c] = cand_idx[(size_t)b * CAND_MAX + c];
  __syncthreads();
  finalize_core(b, tid, wid, l, cnt, W_enc, b_enc, WdecT, b_dec,
                xr, cv, ci, sv, si, zout, xhat);
}

// ---------------- K4+K5 (fused): select+finalize ----------------
__global__ __launch_bounds__(256) void fused_finalize_kernel(
    const unsigned short* __restrict__ za,
    const float* __restrict__ x, const float* __restrict__ W_enc,
    const float* __restrict__ b_enc,
    const float* __restrict__ WdecT, const float* __restrict__ b_dec,
    float* __restrict__ zout, float* __restrict__ xhat) {
  int b = blockIdx.x, tid = threadIdx.x;
  int wid = tid >> 6, l = tid & 63;
  __shared__ __align__(16) float xr[ND];
  __shared__ float cv[CAND_MAX];
  __shared__ int   ci[CAND_MAX];
  __shared__ float sv[NK];
  __shared__ int   si[NK];
  __shared__ int   wcnt[4];
  __shared__ int   lcnt;

  const uint4* zrow = (const uint4*)(za + (size_t)b * NH);
  uint4 v[8];
#pragma unroll
  for (int i = 0; i < 8; ++i) v[i] = zrow[tid + 256 * i];
  const float4* xrow = (const float4*)(x + (size_t)b * ND);
  for (int i = tid; i < ND / 4; i += 256) ((float4*)xr)[i] = xrow[i];

  float thr = bisect_thr(v, wcnt, tid);
  if (tid == 0) lcnt = 0;
  __syncthreads();
#pragma unroll
  for (int i = 0; i < 8; ++i) {
    const unsigned* p = (const unsigned*)&v[i];
#pragma unroll
    for (int e = 0; e < 4; ++e) {
      unsigned u = p[e];
      int hbase = (tid + 256 * i) * 8 + e * 2;
      float f0 = __uint_as_float((u & 0xFFFFu) << 16);
      float f1 = __uint_as_float(u & 0xFFFF0000u);
      if (f0 >= thr) { int s = atomicAdd(&lcnt, 1); if (s < CAND_MAX) ci[s] = hbase; }
      if (f1 >= thr) { int s = atomicAdd(&lcnt, 1); if (s < CAND_MAX) ci[s] = hbase + 1; }
    }
  }
  __syncthreads();
  int cnt = (lcnt < CAND_MAX) ? lcnt : CAND_MAX;

  finalize_core(b, tid, wid, l, cnt, W_enc, b_enc, WdecT, b_dec,
                xr, cv, ci, sv, si, zout, xhat);
}

// ---------------- launcher ----------------
extern "C" void kernel_launch(void* const* d_in, const int* in_sizes, int n_in,
                              void* d_out, int out_size, void* d_ws, size_t ws_size,
                              hipStream_t stream) {
  const float* x     = (const float*)d_in[0];
  const float* W_enc = (const float*)d_in[1];
  const float* b_enc = (const float*)d_in[2];
  const float* W_dec = (const float*)d_in[3];
  const float* b_dec = (const float*)d_in[4];

  float* xhat = (float*)d_out;
  float* zout = (float*)d_out + (size_t)NB * ND;

  char* ws = (char*)d_ws;
  unsigned short* x_bf    = (unsigned short*)(ws + OFF_XBF);
  unsigned short* wenc_bf = (unsigned short*)(ws + OFF_WENCB);
  float*          wdecT   = (float*)(ws + OFF_WDECT);
  int*            cidx    = (int*)(ws + OFF_CIDX);
  int*            ccnt    = (int*)(ws + OFF_CCNT);

  bool fused = ws_size >= OFF_ZA + ZA_BYTES;   // constant across calls -> capture-safe
  unsigned short* za = fused ? (unsigned short*)(ws + OFF_ZA)
                             : (unsigned short*)zout;

  cast_bf16_kernel<<<1024, 256, 0, stream>>>(x, x_bf, NB * ND / 4);
  cast_bf16_kernel<<<2048, 256, 0, stream>>>(W_enc, wenc_bf, NH * ND / 4);
  transpose_kernel<<<dim3(NH / 32, ND / 32), dim3(32, 8), 0, stream>>>(W_dec, wdecT);
  encode_gemm_kernel<<<(NB / 256) * (NH / 256), 512, 0, stream>>>(x_bf, wenc_bf, b_enc, za);
  if (fused) {
    fused_finalize_kernel<<<NB, 256, 0, stream>>>(za, x, W_enc, b_enc, wdecT, b_dec, zout, xhat);
  } else {
    select_kernel<<<NB, 256, 0, stream>>>(za, cidx, ccnt);
    finalize_kernel<<<NB, 256, 0, stream>>>(x, W_enc, b_enc, cidx, ccnt, wdecT, b_dec, zout, xhat);
  }
}